// Round 9
// baseline (33.434 us; speedup 1.0000x reference)
//
#include <hip/hip_runtime.h>
#include <math.h>

// MoE router: x [16384, 2048] f32, gate_w [8, 2048] f32
// outputs (concatenated f32): weights [16384,2] | mask [8,2,16384] | logits [16384,8]
//
// Pure-TLP structure: 2048 blocks x 256 threads = 8192 waves -> 100% of the
// 256CU x 32-wave slot capacity (previous rounds ran at 50%). No LDS, no
// barriers, no manual pipelining; <=64 VGPR so 8 waves/SIMD hide latency.
// Wave owns 2 rows; 8 col-chunks of 1KB; gates re-read per chunk from L2.

constexpr int kN = 16384;
constexpr int kD = 2048;
constexpr int kE = 8;

using f4 = __attribute__((ext_vector_type(4))) float;

__global__ __launch_bounds__(256, 8)
void moe_router_kernel(const float* __restrict__ x,
                       const float* __restrict__ gw,
                       float* __restrict__ out)
{
    const int lane = threadIdx.x & 63;
    const int wv   = threadIdx.x >> 6;
    const int n0   = blockIdx.x * 8 + wv * 2;      // 2 rows per wave

    const float* xr = x + (long)n0 * kD;

    float acc0[8], acc1[8];
#pragma unroll
    for (int e = 0; e < 8; ++e) { acc0[e] = 0.f; acc1[e] = 0.f; }

#pragma unroll 1
    for (int it = 0; it < 8; ++it) {
        const int c = it * 256 + lane * 4;
        // x first (HBM, longest latency)
        const f4 xv0 = *reinterpret_cast<const f4*>(xr + c);
        const f4 xv1 = *reinterpret_cast<const f4*>(xr + kD + c);
        // experts in two batches of 4 -> only 16 g-regs live at a time
        {
            f4 g[4];
#pragma unroll
            for (int e = 0; e < 4; ++e)
                g[e] = *reinterpret_cast<const f4*>(gw + e * kD + c);
#pragma unroll
            for (int e = 0; e < 4; ++e) {
                float t0 = fmaf(xv0.x, g[e].x, acc0[e]);
                t0 = fmaf(xv0.y, g[e].y, t0);
                t0 = fmaf(xv0.z, g[e].z, t0);
                acc0[e] = fmaf(xv0.w, g[e].w, t0);
                float t1 = fmaf(xv1.x, g[e].x, acc1[e]);
                t1 = fmaf(xv1.y, g[e].y, t1);
                t1 = fmaf(xv1.z, g[e].z, t1);
                acc1[e] = fmaf(xv1.w, g[e].w, t1);
            }
        }
        {
            f4 g[4];
#pragma unroll
            for (int e = 0; e < 4; ++e)
                g[e] = *reinterpret_cast<const f4*>(gw + (e + 4) * kD + c);
#pragma unroll
            for (int e = 0; e < 4; ++e) {
                float t0 = fmaf(xv0.x, g[e].x, acc0[e + 4]);
                t0 = fmaf(xv0.y, g[e].y, t0);
                t0 = fmaf(xv0.z, g[e].z, t0);
                acc0[e + 4] = fmaf(xv0.w, g[e].w, t0);
                float t1 = fmaf(xv1.x, g[e].x, acc1[e + 4]);
                t1 = fmaf(xv1.y, g[e].y, t1);
                t1 = fmaf(xv1.z, g[e].z, t1);
                acc1[e + 4] = fmaf(xv1.w, g[e].w, t1);
            }
        }
    }

    // ---- fold: 48 shuffles. Level 1 folds the row pair (lane keeps row
    // lane&1), levels 2..32 sum across the rest of the wave. ----
    const int rp = lane & 1;
    float a1[8];
#pragma unroll
    for (int e = 0; e < 8; ++e) {
        const float mine  = rp ? acc1[e] : acc0[e];
        const float other = rp ? acc0[e] : acc1[e];
        a1[e] = mine + __shfl_xor(other, 1);
    }
#pragma unroll
    for (int e = 0; e < 8; ++e) {
        float v = a1[e];
        v += __shfl_xor(v, 2);
        v += __shfl_xor(v, 4);
        v += __shfl_xor(v, 8);
        v += __shfl_xor(v, 16);
        v += __shfl_xor(v, 32);
        a1[e] = v;   // logit of (row = n0 + (lane&1), expert = e)
    }

    // ---- per-lane top-2 (lowest-index tie-break) on its own row ----
    int s0 = 0; float b0 = a1[0];
#pragma unroll
    for (int e = 1; e < 8; ++e)
        if (a1[e] > b0) { b0 = a1[e]; s0 = e; }
    int s1 = 0; float b1 = -3.4e38f;
#pragma unroll
    for (int e = 0; e < 8; ++e) {
        const bool t = (e != s0) && (a1[e] > b1);
        b1 = t ? a1[e] : b1;
        s1 = t ? e : s1;
    }
    const float d  = expf(b1 - b0);          // <= 1
    const float w0 = 1.0f / (1.0f + d);      // p0/(p0+p1)
    const float w1 = d * w0;

    float* out_w = out;                            // [N, 2]
    float* out_m = out + 2 * kN;                   // [E, 2, N]
    float* out_l = out + 2 * kN + 2 * kE * kN;     // [N, 8]

    const int row = lane & 1;                      // this lane's row parity

    // mask: lanes 0..31 -> (e = lane>>2, k = (lane>>1)&1, row = lane&1)
    if (lane < 32) {
        const int em = lane >> 2;
        const int km = (lane >> 1) & 1;
        const int ss = km ? s1 : s0;
        out_m[(long)em * (2 * kN) + (long)km * kN + (n0 + row)] =
            (ss == em) ? 1.0f : 0.0f;
    }
    // weights: lanes 0..3 -> (k = lane>>1, row = lane&1)
    if (lane < 4)
        out_w[(long)(n0 + row) * 2 + (lane >> 1)] = (lane >> 1) ? w1 : w0;
    // logits: lanes 0..15 -> (e = lane>>1, row = lane&1)
    if (lane < 16) {
        const int el = lane >> 1;
        float v = a1[0];
#pragma unroll
        for (int e = 1; e < 8; ++e)
            v = (el == e) ? a1[e] : v;
        out_l[(long)(n0 + row) * 8 + el] = v;
    }
}

extern "C" void kernel_launch(void* const* d_in, const int* in_sizes, int n_in,
                              void* d_out, int out_size, void* d_ws, size_t ws_size,
                              hipStream_t stream)
{
    (void)in_sizes; (void)n_in; (void)d_ws; (void)ws_size; (void)out_size;
    const float* x  = (const float*)d_in[0];
    const float* gw = (const float*)d_in[1];
    float* out = (float*)d_out;

    dim3 grid(kN / 8);    // 2048 blocks x 8 rows -> 8 blocks/CU, 32 waves/CU
    dim3 block(256);
    moe_router_kernel<<<grid, block, 0, stream>>>(x, gw, out);
}